// Round 12
// baseline (202.601 us; speedup 1.0000x reference)
//
#include <hip/hip_runtime.h>
#include <hip/hip_bf16.h>

// out[512, 65536] = inputs[512,256] @ features[65536,256]^T  (fp32 in/out)
//
// v13 = v12 (zero-barrier, wave-private As, counted vmcnt) + the WAR fix:
// a sched_barrier(0) at the TOP of each step, before the DMA-issue block.
// v12's failure mechanism: iteration t+1's DMA for tile t+2 (which overwrites
// As[t&1]) sat in the same scheduling region as step t's ds_reads of As[t&1]
// and could be hoisted above them -> once issued, the async LDS write could
// land before the reads executed. With the leading SB, the DMA issue cannot
// cross above the previous step's reads; program-order issue then makes the
// race impossible (the DMA request doesn't exist until the reads have issued).
//   - BN=64, 4 waves stacked in M: As tiles are WAVE-PRIVATE (DMA->read
//     dependency wave-local; no s_barrier in main loop).
//   - As[2][wave][64r x 32k] dbuf; tile t+1 DMA issued at step t start.
//   - Counted waits (4 DMA + 2 stores/step, in-order retirement; sound under
//     any in-region reordering): t<=8 -> vmcnt(4); 9..14 -> vmcnt(6);
//     t=15 -> vmcnt(2). Stores never force-drained.
//   - As XOR-swizzle folded into DMA SOURCE slot (linear dest, rule #21);
//     read slot pA = lh ^ (lane&3). Bs: v8-proven XOR swizzle.
//   - ONE __syncthreads total (after Bs staging / tile-0 drain).

#define M_DIM 512
#define N_DIM 65536
#define K_DIM 256
#define BN 64
#define BK 32

typedef __bf16 bf16x8 __attribute__((ext_vector_type(8)));
typedef float f32x4 __attribute__((ext_vector_type(4)));

// ---- kernel 1: inputs [512][256] fp32 -> bf16 ws, row-major ----
__global__ __launch_bounds__(256) void cvt_inputs(const float* __restrict__ A,
                                                  __bf16* __restrict__ Aw) {
    const int t = blockIdx.x * 256 + threadIdx.x;   // 16384 threads x 8 elems
    const float* src = A + (size_t)t * 8;
    f32x4 v0 = *(const f32x4*)src;
    f32x4 v1 = *(const f32x4*)(src + 4);
    bf16x8 h;
    h[0] = (__bf16)v0[0]; h[1] = (__bf16)v0[1];
    h[2] = (__bf16)v0[2]; h[3] = (__bf16)v0[3];
    h[4] = (__bf16)v1[0]; h[5] = (__bf16)v1[1];
    h[6] = (__bf16)v1[2]; h[7] = (__bf16)v1[3];
    *(bf16x8*)(Aw + (size_t)t * 8) = h;
}

static __device__ __forceinline__ void gload_lds16(const __bf16* g, __bf16* l) {
    __builtin_amdgcn_global_load_lds(
        (const __attribute__((address_space(1))) void*)g,
        (__attribute__((address_space(3))) void*)l, 16, 0, 0);
}

__global__ __launch_bounds__(256, 2) void hm_gemm_bt(
    const __bf16* __restrict__ Aw,  // [512][256] bf16 ws (L2-resident)
    const float*  __restrict__ B,   // features [65536][256] fp32
    float* __restrict__ C)          // out [512][65536] fp32
{
    __shared__ __align__(16) __bf16 Bs[BN * K_DIM];   // 32 KB, full-K B panel
    __shared__ __align__(16) __bf16 As[2][4][2048];   // 32 KB: [buf][wave][64rx32k]

    const int tid  = threadIdx.x;
    const int lane = tid & 63;
    const int wave = tid >> 6;            // 4 waves stacked in M, 64 rows each
    const int n0   = blockIdx.x * BN;     // grid = 1024 panels

    const int lrow = lane & 15;
    const int lh   = lane >> 4;           // 0..3
    const int lx   = lane & 7;            // Bs XOR key

    // A-DMA lane geometry: chunk c: lane l writes LDS elems c*512 + l*8
    // -> row_local = c*16 + (l>>2), phys 16B slot l&3. Pre-swizzled source:
    // fetch logical k-slot (l&3)^(row&3) = (l&3)^((l>>2)&3)  (lane-const).
    const int arow = lane >> 2;                        // row within 16-row chunk
    const int aslt = (lane & 3) ^ ((lane >> 2) & 3);   // source k-slot
    // As read: logical slot lh at row (row&3 == lane&3) -> phys lane-const:
    const int pA = lh ^ (lane & 3);

    // ---- issue tile 0 DMA (mp=0, kb=0) first: flies during Bs staging
    #pragma unroll
    for (int c = 0; c < 4; ++c)
        gload_lds16(Aw + (size_t)(wave * 64 + c * 16 + arow) * K_DIM + aslt * 8,
                    &As[0][wave][c * 512]);

    // ---- stage B panel once: 64 rows x 256 k, fp32 -> bf16, XOR-swizzled
    #pragma unroll 4
    for (int it = 0; it < 8; ++it) {
        const int cc  = it * 256 + tid;   // 0..2047 bf16x8 slots
        const int row = cc >> 5;          // 0..63
        const int s   = cc & 31;
        const float* src = B + (size_t)(n0 + row) * K_DIM + s * 8;
        f32x4 v0 = *(const f32x4*)(src);
        f32x4 v1 = *(const f32x4*)(src + 4);
        bf16x8 h;
        h[0] = (__bf16)v0[0]; h[1] = (__bf16)v0[1];
        h[2] = (__bf16)v0[2]; h[3] = (__bf16)v0[3];
        h[4] = (__bf16)v1[0]; h[5] = (__bf16)v1[1];
        h[6] = (__bf16)v1[2]; h[7] = (__bf16)v1[3];
        const int sst = s ^ (row & 7);
        *(bf16x8*)&Bs[row * K_DIM + sst * 8] = h;
    }
    __syncthreads();   // ONLY barrier: Bs ready + tile-0 DMA drained (vmcnt 0)

    f32x4 acc[4][4], accs[4][4];

    // ---- 16 steps: t -> (mp = t>>3, kb = t&7). NO barriers. Free-running.
    #pragma unroll
    for (int t = 0; t < 16; ++t) {
        const int kb = t & 7;

        // WAR fence: the DMA below overwrites As[(t+1)&1], which step t-1
        // finished reading BEFORE this point. Pin it so it cannot hoist
        // above the previous step's ds_reads.
        __builtin_amdgcn_sched_barrier(0);

        // issue NEXT tile's DMA into the other buffer (wave-private dest)
        if (t < 15) {
            const int tn  = t + 1;
            const int mpn = tn >> 3;
            const int kbn = tn & 7;
            #pragma unroll
            for (int c = 0; c < 4; ++c)
                gload_lds16(Aw + (size_t)(mpn * 256 + wave * 64 + c * 16 + arow)
                                 * K_DIM + kbn * BK + aslt * 8,
                            &As[tn & 1][wave][c * 512]);
        }
        // pin: DMAs stay oldest vmem ops of this step
        __builtin_amdgcn_sched_barrier(0);
        // counted wait: tile t landed; fresh stores stay in flight.
        // Queue math (4 DMA + 2 stores/step, in-order retirement; sound
        // under any in-region store/DMA ordering):
        if (t <= 8)      asm volatile("s_waitcnt vmcnt(4)" ::: "memory");
        else if (t < 15) asm volatile("s_waitcnt vmcnt(6)" ::: "memory");
        else             asm volatile("s_waitcnt vmcnt(2)" ::: "memory");
        __builtin_amdgcn_sched_barrier(0);

        if (kb == 0) {
            #pragma unroll
            for (int i = 0; i < 4; ++i)
                #pragma unroll
                for (int j = 0; j < 4; ++j)
                    acc[i][j] = f32x4{0.f, 0.f, 0.f, 0.f};
        }

        bf16x8 af[4], bfr[4];
        #pragma unroll
        for (int i = 0; i < 4; ++i)
            af[i] = *(const bf16x8*)
                &As[t & 1][wave][(i * 16 + lrow) * BK + pA * 8];
        #pragma unroll
        for (int j = 0; j < 4; ++j) {
            const int row = j * 16 + lrow;
            const int pos = (kb * 4 + lh) ^ lx;
            bfr[j] = *(const bf16x8*)&Bs[row * K_DIM + pos * 8];
        }
        #pragma unroll
        for (int i = 0; i < 4; ++i)
            #pragma unroll
            for (int j = 0; j < 4; ++j)
                acc[i][j] = __builtin_amdgcn_mfma_f32_16x16x32_bf16(
                    bfr[j], af[i], acc[i][j], 0, 0, 0);   // swapped: D.row -> n

        // ---- interleaved C stores: 2 per step, previous mp's tile (t>=8)
        if (t >= 8) {
            #pragma unroll
            for (int q = 0; q < 2; ++q) {
                const int sidx = (t - 8) * 2 + q;     // 0..15 over mp0
                const int i = sidx >> 2;
                const int j = sidx & 3;
                const size_t rowb =
                    (size_t)(/*mp0*/ wave * 64 + i * 16 + lrow) * N_DIM;
                *(f32x4*)(C + rowb + (n0 + j * 16 + lh * 4)) = accs[i][j];
            }
        }

        // mp finished: shadow-copy acc so stores can trail
        if (kb == 7) {
            #pragma unroll
            for (int i = 0; i < 4; ++i)
                #pragma unroll
                for (int j = 0; j < 4; ++j)
                    accs[i][j] = acc[i][j];
        }
    }

    // ---- final mp (mp=1) stores
    {
        #pragma unroll
        for (int i = 0; i < 4; ++i) {
            const size_t rowb =
                (size_t)(256 + wave * 64 + i * 16 + lrow) * N_DIM;
            #pragma unroll
            for (int j = 0; j < 4; ++j)
                *(f32x4*)(C + rowb + (n0 + j * 16 + lh * 4)) = accs[i][j];
        }
    }
}

extern "C" void kernel_launch(void* const* d_in, const int* in_sizes, int n_in,
                              void* d_out, int out_size, void* d_ws, size_t ws_size,
                              hipStream_t stream) {
    // setup_inputs order: inputs, indexes, features, mIoU, IoU
    const float* inputs   = (const float*)d_in[0];
    const float* features = (const float*)d_in[2];
    float* out = (float*)d_out;
    __bf16* Aw = (__bf16*)d_ws;          // 256 KB of workspace

    hipLaunchKernelGGL(cvt_inputs, dim3(M_DIM * K_DIM / (256 * 8)), dim3(256),
                       0, stream, inputs, Aw);

    hipLaunchKernelGGL(hm_gemm_bt, dim3(N_DIM / BN), dim3(256), 0, stream,
                       Aw, features, out);
}